// Round 1
// baseline (178.797 us; speedup 1.0000x reference)
//
#include <hip/hip_runtime.h>

#define EPS 1e-5f

#define BATCH 16
#define LEN   1024
#define C0    8
#define C1    32
#define C2    64
#define NODES 128
#define NF1   100
#define NF2   128

// workspace layout (float offsets)
#define OFF_STATS 0         // s1[32] q1[32] s2[64] q2[64] = 192
#define OFF_ZZ    192       // 16*100 = 1600
#define OFF_Z     1792      // 16*128*64 = 131072
#define OFF_C1    132864    // 16*32*1024 = 524288
#define OFF_C2    657152    // 16*64*1024 = 1048576
#define ZERO_FLOATS (192 + 1600 + 131072)

// ---------------- K1: conv1 (8->32, K=5, pad 2) + bias, write c1, accumulate BN1 stats
__global__ __launch_bounds__(256)
void k1_conv1(const float* __restrict__ x, const float* __restrict__ w,
              const float* __restrict__ bias, float* __restrict__ c1,
              float* __restrict__ stats) {
    int tid = threadIdx.x;
    int ltile = blockIdx.x, n = blockIdx.y, zh = blockIdx.z;
    int l = ltile * 256 + tid;

    float xr[5][8];
#pragma unroll
    for (int dl = 0; dl < 5; ++dl) {
        int lw = l + dl - 2;
        if (lw >= 0 && lw < LEN) {
            const float4* p = (const float4*)(x + ((size_t)n * LEN + lw) * C0);
            float4 a = p[0], b4 = p[1];
            xr[dl][0] = a.x; xr[dl][1] = a.y; xr[dl][2] = a.z; xr[dl][3] = a.w;
            xr[dl][4] = b4.x; xr[dl][5] = b4.y; xr[dl][6] = b4.z; xr[dl][7] = b4.w;
        } else {
#pragma unroll
            for (int ci = 0; ci < 8; ++ci) xr[dl][ci] = 0.f;
        }
    }

    __shared__ float red[4][16][2];
    int lane = tid & 63, wave = tid >> 6;

    for (int cl = 0; cl < 16; ++cl) {
        int c = zh * 16 + cl;
        float acc = bias[c];
        const float* wc = w + c * 40;   // w[c][ci][dl], 40 consecutive floats
#pragma unroll
        for (int ci = 0; ci < 8; ++ci)
#pragma unroll
            for (int dl = 0; dl < 5; ++dl)
                acc += xr[dl][ci] * wc[ci * 5 + dl];
        c1[((size_t)n * C1 + c) * LEN + l] = acc;

        float s = acc, q = acc * acc;
#pragma unroll
        for (int off = 32; off >= 1; off >>= 1) {
            s += __shfl_xor(s, off);
            q += __shfl_xor(q, off);
        }
        if (lane == 0) { red[wave][cl][0] = s; red[wave][cl][1] = q; }
    }
    __syncthreads();
    if (tid < 32) {
        int cl = tid >> 1, kind = tid & 1;
        float v = red[0][cl][kind] + red[1][cl][kind] + red[2][cl][kind] + red[3][cl][kind];
        atomicAdd(&stats[kind * 32 + zh * 16 + cl], v);
    }
}

// ---------------- K3: BN1+ReLU (fused on load) -> conv2 (32->64, K=5) + bias, write c2, accumulate BN2 stats
__global__ __launch_bounds__(256)
void k3_conv2(const float* __restrict__ c1, const float* __restrict__ w,
              const float* __restrict__ bias,
              const float* __restrict__ g1, const float* __restrict__ bb1,
              float* __restrict__ c2, float* __restrict__ stats) {
    int tid = threadIdx.x;
    int ltile = blockIdx.x, n = blockIdx.y;
    int lbase = ltile * 64;

    __shared__ float sc1[32], sh1[32];
    __shared__ __align__(16) float a1[32 * 68];
    __shared__ float red[4][16][2];

    if (tid < 32) {
        float s = stats[tid], q = stats[32 + tid];
        float mean = s * (1.f / 16384.f);
        float var = q * (1.f / 16384.f) - mean * mean;
        float rs = rsqrtf(var + EPS);
        float sc = g1[tid] * rs;
        sc1[tid] = sc;
        sh1[tid] = bb1[tid] - mean * sc;
    }
    __syncthreads();

    for (int idx = tid; idx < 32 * 68; idx += 256) {
        int ci = idx / 68, lo = idx - ci * 68;
        int lg = lbase + lo - 2;
        float v = 0.f;
        if (lg >= 0 && lg < LEN) v = c1[((size_t)n * C1 + ci) * LEN + lg];
        a1[idx] = fmaxf(0.f, v * sc1[ci] + sh1[ci]);
    }
    __syncthreads();

    int l = tid & 63;
    int wave = __builtin_amdgcn_readfirstlane(tid >> 6);
    int cobase = wave * 16;

    float acc[16];
#pragma unroll
    for (int u = 0; u < 16; ++u) acc[u] = bias[cobase + u];

    for (int ci = 0; ci < 32; ++ci) {
        float v0 = a1[ci * 68 + l + 0];
        float v1 = a1[ci * 68 + l + 1];
        float v2 = a1[ci * 68 + l + 2];
        float v3 = a1[ci * 68 + l + 3];
        float v4 = a1[ci * 68 + l + 4];
#pragma unroll
        for (int u = 0; u < 16; ++u) {
            const float* wp = w + ((size_t)(cobase + u) * 32 + ci) * 5; // wave-uniform -> s_loads
            acc[u] += v0 * wp[0] + v1 * wp[1] + v2 * wp[2] + v3 * wp[3] + v4 * wp[4];
        }
    }

    int lane = tid & 63;
    int lg = lbase + l;
#pragma unroll
    for (int u = 0; u < 16; ++u)
        c2[((size_t)n * C2 + cobase + u) * LEN + lg] = acc[u];

    for (int u = 0; u < 16; ++u) {
        float s = acc[u], q = acc[u] * acc[u];
#pragma unroll
        for (int off = 32; off >= 1; off >>= 1) {
            s += __shfl_xor(s, off);
            q += __shfl_xor(q, off);
        }
        if (lane == 0) { red[wave][u][0] = s; red[wave][u][1] = q; }
    }
    __syncthreads();
    if (tid < 128) {
        int wv = tid >> 5, rem = tid & 31;
        int u = rem >> 1, kind = rem & 1;
        int ch = wv * 16 + u;
        atomicAdd(&stats[64 + kind * 64 + ch], red[wv][u][kind]);
    }
}

// ---------------- K5: BN2+ReLU (fused) + max-product pooling, atomicMax into z (all values >= 0)
__global__ __launch_bounds__(256)
void k5_pool(const float* __restrict__ bmat, const float* __restrict__ c2,
             const float* __restrict__ g2, const float* __restrict__ bb2,
             const float* __restrict__ stats, float* __restrict__ z) {
    int tid = threadIdx.x;
    int jt = blockIdx.x, is = blockIdx.y, n = blockIdx.z;
    int jbase = jt * 32;
    int ibase0 = is * 256;

    __shared__ float sc2[64], sh2[64];
    __shared__ __align__(16) float bt[64 * 34];
    __shared__ __align__(16) float ht[64 * 68];

    if (tid < 64) {
        float s = stats[64 + tid], q = stats[128 + tid];
        float mean = s * (1.f / 16384.f);
        float var = q * (1.f / 16384.f) - mean * mean;
        float rs = rsqrtf(var + EPS);
        float sc = g2[tid] * rs;
        sc2[tid] = sc;
        sh2[tid] = bb2[tid] - mean * sc;
    }
    __syncthreads();

    float mx[2][4];
#pragma unroll
    for (int a = 0; a < 2; ++a)
#pragma unroll
        for (int c = 0; c < 4; ++c) mx[a][c] = 0.f;

    int jj = (tid >> 4) * 2, kk = (tid & 15) * 4;

    for (int ic = 0; ic < 4; ++ic) {
        int ib = ibase0 + ic * 64;
        // stage b tile [64 i][32 j], pad stride 34
        {
            int il = tid >> 2, jq = tid & 3;
            const float4* p = (const float4*)(bmat + ((size_t)n * LEN + ib + il) * NODES + jbase + jq * 8);
            float4 a = p[0], b4 = p[1];
            float* d = &bt[il * 34 + jq * 8];
            d[0] = a.x; d[1] = a.y; d[2] = a.z; d[3] = a.w;
            d[4] = b4.x; d[5] = b4.y; d[6] = b4.z; d[7] = b4.w;
        }
        // stage h tile [64 i][64 k] transposed from c2 (n,k,l), BN2+ReLU applied, pad stride 68
        {
            int kc = tid >> 2, iq = tid & 3;
            float sc = sc2[kc], sh = sh2[kc];
            const float4* p = (const float4*)(c2 + ((size_t)n * C2 + kc) * LEN + ib + iq * 16);
#pragma unroll
            for (int r = 0; r < 4; ++r) {
                float4 hv = p[r];
                int i0 = iq * 16 + r * 4;
                ht[(i0 + 0) * 68 + kc] = fmaxf(0.f, hv.x * sc + sh);
                ht[(i0 + 1) * 68 + kc] = fmaxf(0.f, hv.y * sc + sh);
                ht[(i0 + 2) * 68 + kc] = fmaxf(0.f, hv.z * sc + sh);
                ht[(i0 + 3) * 68 + kc] = fmaxf(0.f, hv.w * sc + sh);
            }
        }
        __syncthreads();
#pragma unroll 4
        for (int i = 0; i < 64; ++i) {
            float2 bv = *(const float2*)&bt[i * 34 + jj];
            float4 hv = *(const float4*)&ht[i * 68 + kk];
            mx[0][0] = fmaxf(mx[0][0], bv.x * hv.x);
            mx[0][1] = fmaxf(mx[0][1], bv.x * hv.y);
            mx[0][2] = fmaxf(mx[0][2], bv.x * hv.z);
            mx[0][3] = fmaxf(mx[0][3], bv.x * hv.w);
            mx[1][0] = fmaxf(mx[1][0], bv.y * hv.x);
            mx[1][1] = fmaxf(mx[1][1], bv.y * hv.y);
            mx[1][2] = fmaxf(mx[1][2], bv.y * hv.z);
            mx[1][3] = fmaxf(mx[1][3], bv.y * hv.w);
        }
        __syncthreads();
    }
#pragma unroll
    for (int a = 0; a < 2; ++a)
#pragma unroll
        for (int c = 0; c < 4; ++c) {
            int j = jbase + jj + a, k = kk + c;
            atomicMax((unsigned int*)&z[((size_t)n * NODES + j) * 64 + k],
                      __float_as_uint(mx[a][c]));
        }
}

// ---------------- K6: FC1 partial dots: zz[n][f] += sum over k-chunk of z[n][idx]*w1[f][idx]
__global__ __launch_bounds__(256)
void k6_fc1(const float* __restrict__ zbuf, const float* __restrict__ w1,
            float* __restrict__ zz) {
    int tid = threadIdx.x;
    int f = blockIdx.x, kq = blockIdx.y;
    int base = kq * 2048;

    float acc[16];
#pragma unroll
    for (int n = 0; n < 16; ++n) acc[n] = 0.f;

    for (int q = 0; q < 8; ++q) {
        int idx = base + q * 256 + tid;
        float wv = w1[(size_t)f * 8192 + idx];
#pragma unroll
        for (int n = 0; n < 16; ++n)
            acc[n] += wv * zbuf[(size_t)n * 8192 + idx];
    }

    __shared__ float red[4][16];
    int lane = tid & 63, wave = tid >> 6;
    for (int n = 0; n < 16; ++n) {
        float s = acc[n];
#pragma unroll
        for (int off = 32; off >= 1; off >>= 1) s += __shfl_xor(s, off);
        if (lane == 0) red[wave][n] = s;
        // red slot unique per (wave,n); written once
        if (n == 15) {} // keep loop simple
    }
    __syncthreads();
    if (tid < 16) {
        float v = red[0][tid] + red[1][tid] + red[2][tid] + red[3][tid];
        atomicAdd(&zz[tid * NF1 + f], v);
    }
}

// ---------------- K7: +b1, BN3 (per-feature over batch), ReLU, FC2 (+b2) -> out (16,128)
__global__ __launch_bounds__(128)
void k7_final(const float* __restrict__ zz, const float* __restrict__ b1f,
              const float* __restrict__ g3, const float* __restrict__ b3,
              const float* __restrict__ w2, const float* __restrict__ b2f,
              float* __restrict__ out) {
    int tid = threadIdx.x;
    int n = blockIdx.x;

    __shared__ float zzl[BATCH * NF1];
    __shared__ float sc3[NF1], sh3[NF1];

    for (int idx = tid; idx < BATCH * NF1; idx += 128) {
        int f = idx % NF1;
        zzl[idx] = zz[idx] + b1f[f];
    }
    __syncthreads();
    if (tid < NF1) {
        float s = 0.f, q = 0.f;
#pragma unroll
        for (int m = 0; m < BATCH; ++m) {
            float v = zzl[m * NF1 + tid];
            s += v; q += v * v;
        }
        float mean = s * (1.f / 16.f);
        float var = q * (1.f / 16.f) - mean * mean;
        float rs = rsqrtf(var + EPS);
        float sc = g3[tid] * rs;
        sc3[tid] = sc;
        sh3[tid] = b3[tid] - mean * sc;
    }
    __syncthreads();
    for (int idx = tid; idx < BATCH * NF1; idx += 128) {
        int f = idx % NF1;
        zzl[idx] = fmaxf(0.f, zzl[idx] * sc3[f] + sh3[f]);
    }
    __syncthreads();

    // tid = output feature o (128)
    float acc = b2f[tid];
    const float* wr = w2 + (size_t)tid * NF1;
    const float* zr = &zzl[n * NF1];
#pragma unroll 4
    for (int f = 0; f < NF1; ++f)
        acc += zr[f] * wr[f];
    out[n * NF2 + tid] = acc;
}

extern "C" void kernel_launch(void* const* d_in, const int* in_sizes, int n_in,
                              void* d_out, int out_size, void* d_ws, size_t ws_size,
                              hipStream_t stream) {
    const float* x    = (const float*)d_in[0];
    const float* bmat = (const float*)d_in[1];
    const float* c1w  = (const float*)d_in[2];
    const float* c1b  = (const float*)d_in[3];
    const float* g1   = (const float*)d_in[4];
    const float* bb1  = (const float*)d_in[5];
    const float* c2w  = (const float*)d_in[6];
    const float* c2b  = (const float*)d_in[7];
    const float* g2   = (const float*)d_in[8];
    const float* bb2  = (const float*)d_in[9];
    const float* w1   = (const float*)d_in[10];
    const float* b1   = (const float*)d_in[11];
    const float* g3   = (const float*)d_in[12];
    const float* b3   = (const float*)d_in[13];
    const float* w2   = (const float*)d_in[14];
    const float* b2   = (const float*)d_in[15];
    float* out = (float*)d_out;
    float* ws  = (float*)d_ws;

    float* stats = ws + OFF_STATS;
    float* zz    = ws + OFF_ZZ;
    float* z     = ws + OFF_Z;
    float* c1    = ws + OFF_C1;
    float* c2    = ws + OFF_C2;

    hipMemsetAsync(ws, 0, ZERO_FLOATS * sizeof(float), stream);
    k1_conv1<<<dim3(4, 16, 2), 256, 0, stream>>>(x, c1w, c1b, c1, stats);
    k3_conv2<<<dim3(16, 16), 256, 0, stream>>>(c1, c2w, c2b, g1, bb1, c2, stats);
    k5_pool<<<dim3(4, 4, 16), 256, 0, stream>>>(bmat, c2, g2, bb2, stats, z);
    k6_fc1<<<dim3(NF1, 4), 256, 0, stream>>>(z, w1, zz);
    k7_final<<<16, 128, 0, stream>>>(zz, b1, g3, b3, w2, b2, out);
}